// Round 1
// 312.032 us; speedup vs baseline: 1.0839x; 1.0839x over previous
//
#include <hip/hip_runtime.h>
#include <cstdint>
#include <cstddef>

#define NEGV 1e12f

typedef __bf16 bf16x8 __attribute__((ext_vector_type(8)));
typedef float f32x4 __attribute__((ext_vector_type(4)));

typedef void __attribute__((address_space(1))) gvoid_t;
typedef void __attribute__((address_space(3))) svoid_t;

__device__ __forceinline__ void gld_lds16(const void* g, void* s) {
  // async global->LDS, 16B per lane, dest = wave-uniform base + lane*16
  __builtin_amdgcn_global_load_lds((gvoid_t*)g, (svoid_t*)s, 16, 0, 0);
}

__device__ __forceinline__ unsigned short f2bf(float f) {
  union { float f; unsigned u; } v; v.f = f;
  unsigned r = v.u + 0x7FFFu + ((v.u >> 16) & 1u);  // RNE
  return (unsigned short)(r >> 16);
}

// ---------------------------------------------------------------------------
// K0: transpose + cvt W (768x512 fp32, K-major) -> Wt (1024x768 bf16, rows = N,
// contiguous K). Rows 0..511 = Ws^T, 512..1023 = We^T.
// ---------------------------------------------------------------------------
__global__ __launch_bounds__(256)
void k0_transpose(const float* __restrict__ Ws, const float* __restrict__ We,
                  unsigned short* __restrict__ Wt) {
  __shared__ float tile[32][33];
  const float* W = blockIdx.z ? We : Ws;
  const int n0 = blockIdx.x * 32;
  const int k0 = blockIdx.y * 32;
  const int tx = threadIdx.x & 31;
  const int ty = threadIdx.x >> 5;  // 0..7
#pragma unroll
  for (int i = 0; i < 4; i++)
    tile[ty + i * 8][tx] = W[(size_t)(k0 + ty + i * 8) * 512 + n0 + tx];
  __syncthreads();
#pragma unroll
  for (int i = 0; i < 4; i++) {
    const int n = n0 + ty + i * 8;
    Wt[(size_t)(blockIdx.z * 512 + n) * 768 + k0 + tx] = f2bf(tile[tx][ty + i * 8]);
  }
}

// ---------------------------------------------------------------------------
// K1: start/end projections. C[4096][1024] = A[4096][768] @ W[768][1024] + bias,
// then RoPE + 1/8 scale, stored bf16 to staging [bo][s][64].
// 128x128 tiles, BK=64, 4 waves each 64x64 (4x4 MFMA tiles of 16x16x32 bf16).
// (R2's 128x64 split doubled A traffic/cvt for no measured gain -> reverted.)
// ---------------------------------------------------------------------------
__global__ __launch_bounds__(256, 2)
void k1_proj_rope(const float* __restrict__ A,
                  const float* __restrict__ bs_p,
                  const float* __restrict__ be_p,
                  const unsigned short* __restrict__ Wt,
                  unsigned short* __restrict__ st_start,
                  unsigned short* __restrict__ st_end) {
  // sA padded to 72 elems/row (144B = 9 quads -> bank-balanced b128 reads).
  __shared__ __align__(16) unsigned short sA[128 * 72];
  // sB halves flat [128][32]: 64B row stride is quad-balanced; flat order
  // required by global_load_lds.
  __shared__ __align__(16) unsigned short sB0[128 * 32];
  __shared__ __align__(16) unsigned short sB1[128 * 32];

  const int t = threadIdx.x;
  const int lane = t & 63;
  const int w = t >> 6;
  const int m0 = blockIdx.y * 128;
  const int n0 = blockIdx.x * 128;
  const int wm = (w >> 1) * 64;
  const int wn = (w & 1) * 64;

  f32x4 acc[4][4];
#pragma unroll
  for (int i = 0; i < 4; i++)
#pragma unroll
    for (int j = 0; j < 4; j++) acc[i][j] = (f32x4){0.f, 0.f, 0.f, 0.f};

  for (int kt = 0; kt < 768; kt += 64) {
    __syncthreads();
    // B tiles: async global->LDS (already bf16). 8 chunks of 1KB per half.
#pragma unroll
    for (int h = 0; h < 2; h++) {
      unsigned short* sB = h ? sB1 : sB0;
#pragma unroll
      for (int j = 0; j < 2; j++) {
        const int c = w * 2 + j;               // chunk 0..7
        const int n = c * 16 + (lane >> 2);    // row within tile
        const int kk = (lane & 3) * 8;         // k offset within half
        gld_lds16(Wt + (size_t)(n0 + n) * 768 + kt + h * 32 + kk, sB + c * 512);
      }
    }
    // A tile: fp32 load + cvt + padded ds_write (128x64)
#pragma unroll
    for (int p = 0; p < 8; p++) {
      const int row = p * 16 + (t >> 4);
      const int kk = (t & 15) * 4;
      const float4 v = *(const float4*)(A + (size_t)(m0 + row) * 768 + kt + kk);
      ushort4 bv;
      bv.x = f2bf(v.x); bv.y = f2bf(v.y); bv.z = f2bf(v.z); bv.w = f2bf(v.w);
      *(ushort4*)(sA + row * 72 + kk) = bv;
    }
    __syncthreads();
#pragma unroll
    for (int s = 0; s < 2; s++) {
      const unsigned short* sB = s ? sB1 : sB0;
      bf16x8 af[4], bfr[4];
#pragma unroll
      for (int i = 0; i < 4; i++)
        af[i] = *(const bf16x8*)(sA + (wm + i * 16 + (lane & 15)) * 72 + s * 32 + (lane >> 4) * 8);
#pragma unroll
      for (int j = 0; j < 4; j++)
        bfr[j] = *(const bf16x8*)(sB + (wn + j * 16 + (lane & 15)) * 32 + (lane >> 4) * 8);
#pragma unroll
      for (int i = 0; i < 4; i++)
#pragma unroll
        for (int j = 0; j < 4; j++)
          acc[i][j] = __builtin_amdgcn_mfma_f32_16x16x32_bf16(af[i], bfr[j], acc[i][j], 0, 0, 0);
    }
  }

  // Epilogue: bias + RoPE + 0.125 scale, bf16 store to staging.
  // C/D layout: col = lane&15 (n), row = (lane>>4)*4 + reg (m)  [m89-verified]
#pragma unroll
  for (int j = 0; j < 4; j++) {
    const int n = n0 + wn + j * 16 + (lane & 15);  // 0..1023
    const int isEnd = n >= 512;
    const int nn = n & 511;
    const int o = nn >> 6;
    const int h = nn & 63;
    const float bias = isEnd ? be_p[nn] : bs_p[nn];
    // inv = 10000^(-(h%32)/32) = 2^(-(h%32)*log2(10000)/32)
    const float inv = exp2f(-(float)(h & 31) * 0.41524101186092f);
    const float sgn = (h & 1) ? 1.f : -1.f;  // rot[2k]=-x[2k+1], rot[2k+1]=x[2k]
    unsigned short* dst = isEnd ? st_end : st_start;
#pragma unroll
    for (int i = 0; i < 4; i++) {
#pragma unroll
      for (int r = 0; r < 4; r++) {
        const int m = m0 + wm + i * 16 + (lane >> 4) * 4 + r;
        const int sp = m & 2047;   // s position
        const int b = m >> 11;     // batch
        float val = acc[i][j][r] + bias;
        const float par = __shfl_xor(val, 1, 64);  // partner h^1 (same row)
        float sn, cs;
        __sincosf((float)sp * inv, &sn, &cs);
        const float outv = (val * cs + sgn * par * sn) * 0.125f;  // fold 1/sqrt(64)
        dst[(((size_t)(b * 8 + o) * 2048 + sp) << 6) + h] = f2bf(outv);
      }
    }
  }
}

// ---------------------------------------------------------------------------
// K2: logits[bo][m][n] = sum_d start[bo][m][d]*end[bo][n][d] (scale pre-folded)
// + mask + strict-lower-tril -1e12. 128x128 tiles, K=64 in one shot.
//
// R4 store restructure: the old epilogue stored 4B/lane nontemporal (64B
// segments on rows 8KB apart). With nt bypassing L2 write-combining, each
// 64B segment is a partial 128B-line DRAM write -> RMW amplification; k2 ran
// ~3x over the 6.4 TB/s full-line fill rate. Now ALL output leaves as
// f32x4/lane, 512B-contiguous-per-32-lane (full 128B lines):
//  - fast-path tiles (by>bx, 47% of blocks): value depends only on n;
//    direct coalesced f32x4 nt stores, no LDS.
//  - compute tiles: transpose through LDS in two 64-row phases, reusing the
//    staging LDS as a padded [64][132] f32 buffer (33KB, still 2 blocks/CU).
//    Scatter-writes are 2-way bank aliased (free, m136); b128 readback is
//    exactly the 8-access/bank minimum (132 % 32 == 4 row skew).
// ---------------------------------------------------------------------------
__global__ __launch_bounds__(256, 2)
void k2_logits(const unsigned short* __restrict__ st_start,
               const unsigned short* __restrict__ st_end,
               const float* __restrict__ mask,
               float* __restrict__ out) {
  // union: staging (sA 16KB | sB 16KB) then out-transpose buffer [64][132] f32
  __shared__ __align__(16) unsigned char smem[64 * 132 * 4];  // 33792 B
  unsigned short* sA = (unsigned short*)smem;
  unsigned short* sB = (unsigned short*)(smem + 16384);
  float* sOut = (float*)smem;

  const int t = threadIdx.x;
  const int lane = t & 63;
  const int w = t >> 6;
  const int bo = blockIdx.z;
  const int m0 = blockIdx.y * 128;
  const int n0 = blockIdx.x * 128;
  const int b = bo >> 3;
  const int wm = (w >> 1) * 64;
  const int wn = (w & 1) * 64;

  if (blockIdx.y > blockIdx.x) {
    // Entire tile strictly lower: out = (mv-1)*NEG - NEG, no matmul needed.
    // Value depends only on n -> one f32x4 per thread, 16 coalesced nt stores.
    const int c0 = (t & 31) * 4;                 // col offset within tile
    const f32x4 mv4 = *(const f32x4*)(mask + (size_t)b * 2048 + n0 + c0);
    f32x4 v;
#pragma unroll
    for (int c = 0; c < 4; c++) v[c] = (mv4[c] - 1.0f) * NEGV - NEGV;
#pragma unroll
    for (int it = 0; it < 16; it++) {
      const int row = it * 8 + (t >> 5);
      __builtin_nontemporal_store(
          v, (f32x4*)(out + ((size_t)bo * 2048 + m0 + row) * 2048 + n0 + c0));
    }
    return;
  }

  const size_t abase = ((size_t)bo * 2048 + m0) * 64;
  const size_t bbase = ((size_t)bo * 2048 + n0) * 64;

  // LDS layout k-group-blocked [g][128][8]: lane-contiguous for global_load_lds
  // AND quad-balanced for ds_read_b128 fragment reads.
#pragma unroll
  for (int j = 0; j < 4; j++) {
    const int c = w * 4 + j;          // chunk 0..15 (1KB each)
    const int g = c >> 1;             // k-group 0..7
    const int mr = (c & 1) * 64 + lane;
    gld_lds16(st_start + abase + (size_t)mr * 64 + g * 8, sA + c * 512);
    gld_lds16(st_end + bbase + (size_t)mr * 64 + g * 8, sB + c * 512);
  }

  f32x4 acc[4][4];
#pragma unroll
  for (int i = 0; i < 4; i++)
#pragma unroll
    for (int j = 0; j < 4; j++) acc[i][j] = (f32x4){0.f, 0.f, 0.f, 0.f};

  __syncthreads();

#pragma unroll
  for (int s = 0; s < 2; s++) {
    const int g = s * 4 + (lane >> 4);
    bf16x8 af[4], bfr[4];
#pragma unroll
    for (int i = 0; i < 4; i++)
      af[i] = *(const bf16x8*)(sA + ((size_t)g * 128 + wm + i * 16 + (lane & 15)) * 8);
#pragma unroll
    for (int j = 0; j < 4; j++)
      bfr[j] = *(const bf16x8*)(sB + ((size_t)g * 128 + wn + j * 16 + (lane & 15)) * 8);
#pragma unroll
    for (int i = 0; i < 4; i++)
#pragma unroll
      for (int j = 0; j < 4; j++)
        acc[i][j] = __builtin_amdgcn_mfma_f32_16x16x32_bf16(af[i], bfr[j], acc[i][j], 0, 0, 0);
  }

  // Epilogue: two phases of 64 output rows each. Phase p handles MFMA row
  // tiles i in {2p, 2p+1}. Packed LDS row pr = (w>>1)*32 + ii*16 + q*4 + r
  // maps to global row m_l = (pr&31) + (pr>>5)*64 + p*32 (all waves busy in
  // both the scatter-write and the coalesced-store halves).
  // C/D: col = lane&15 = n, row = (lane>>4)*4+reg = m  [m89-verified]
#pragma unroll
  for (int p = 0; p < 2; p++) {
    __syncthreads();  // staging reads (p=0) / prior stores (p=1) done
#pragma unroll
    for (int j = 0; j < 4; j++) {
      const int n_l = wn + j * 16 + (lane & 15);
      const int n = n0 + n_l;
      const float mv = mask[(size_t)b * 2048 + n];
      const float basev = (mv - 1.0f) * NEGV;  // logits*pad - (1-pad)*NEG
#pragma unroll
      for (int ii = 0; ii < 2; ii++) {
        const int i = p * 2 + ii;
#pragma unroll
        for (int r = 0; r < 4; r++) {
          const int m_l = wm + i * 16 + (lane >> 4) * 4 + r;
          const int m = m0 + m_l;
          float v = acc[i][j][r] * mv + basev;
          if (m > n) v -= NEGV;  // tril(ones,-1): penalize m>n
          const int pr = (w >> 1) * 32 + ii * 16 + (lane >> 4) * 4 + r;
          sOut[pr * 132 + n_l] = v;
        }
      }
    }
    __syncthreads();
    // Coalesced drain: 64 rows x 512B, f32x4 per lane, full 128B lines.
    const int c0 = (t & 31) * 4;
#pragma unroll
    for (int it = 0; it < 8; it++) {
      const int prr = it * 8 + (t >> 5);
      const int m_l = (prr & 31) + ((prr >> 5) << 6) + p * 32;
      const f32x4 v4 = *(const f32x4*)(sOut + prr * 132 + c0);
      __builtin_nontemporal_store(
          v4, (f32x4*)(out + ((size_t)bo * 2048 + m0 + m_l) * 2048 + n0 + c0));
    }
  }
}

// ---------------------------------------------------------------------------
extern "C" void kernel_launch(void* const* d_in, const int* in_sizes, int n_in,
                              void* d_out, int out_size, void* d_ws, size_t ws_size,
                              hipStream_t stream) {
  const float* inputs = (const float*)d_in[0];  // [2][2048][768]
  const float* mask   = (const float*)d_in[1];  // [2][2048]
  const float* Ws     = (const float*)d_in[2];  // [768][512]
  const float* bs     = (const float*)d_in[3];  // [512]
  const float* We     = (const float*)d_in[4];  // [768][512]
  const float* be     = (const float*)d_in[5];  // [512]
  float* out = (float*)d_out;                   // [2][8][2048][2048]

  // workspace: Wt bf16 [1024][768] | start [16][2048][64] | end [16][2048][64]
  unsigned short* Wt = (unsigned short*)d_ws;
  unsigned short* st_start = Wt + 1024 * 768;
  unsigned short* st_end = st_start + 16 * 2048 * 64;

  k0_transpose<<<dim3(16, 24, 2), 256, 0, stream>>>(Ws, We, Wt);
  k1_proj_rope<<<dim3(8, 32), 256, 0, stream>>>(inputs, bs, be, Wt, st_start, st_end);
  k2_logits<<<dim3(16, 16, 16), 256, 0, stream>>>(st_start, st_end, mask, out);
}

// Round 2
// 310.242 us; speedup vs baseline: 1.0902x; 1.0058x over previous
//
#include <hip/hip_runtime.h>
#include <cstdint>
#include <cstddef>

#define NEGV 1e12f

typedef __bf16 bf16x8 __attribute__((ext_vector_type(8)));
typedef float f32x4 __attribute__((ext_vector_type(4)));

typedef void __attribute__((address_space(1))) gvoid_t;
typedef void __attribute__((address_space(3))) svoid_t;

__device__ __forceinline__ void gld_lds16(const void* g, void* s) {
  // async global->LDS, 16B per lane, dest = wave-uniform base + lane*16
  __builtin_amdgcn_global_load_lds((gvoid_t*)g, (svoid_t*)s, 16, 0, 0);
}

__device__ __forceinline__ unsigned short f2bf(float f) {
  union { float f; unsigned u; } v; v.f = f;
  unsigned r = v.u + 0x7FFFu + ((v.u >> 16) & 1u);  // RNE
  return (unsigned short)(r >> 16);
}

// ---------------------------------------------------------------------------
// K0: transpose + cvt W (768x512 fp32, K-major) -> Wt (1024x768 bf16, rows = N,
// contiguous K). Rows 0..511 = Ws^T, 512..1023 = We^T.
// ---------------------------------------------------------------------------
__global__ __launch_bounds__(256)
void k0_transpose(const float* __restrict__ Ws, const float* __restrict__ We,
                  unsigned short* __restrict__ Wt) {
  __shared__ float tile[32][33];
  const float* W = blockIdx.z ? We : Ws;
  const int n0 = blockIdx.x * 32;
  const int k0 = blockIdx.y * 32;
  const int tx = threadIdx.x & 31;
  const int ty = threadIdx.x >> 5;  // 0..7
#pragma unroll
  for (int i = 0; i < 4; i++)
    tile[ty + i * 8][tx] = W[(size_t)(k0 + ty + i * 8) * 512 + n0 + tx];
  __syncthreads();
#pragma unroll
  for (int i = 0; i < 4; i++) {
    const int n = n0 + ty + i * 8;
    Wt[(size_t)(blockIdx.z * 512 + n) * 768 + k0 + tx] = f2bf(tile[tx][ty + i * 8]);
  }
}

// ---------------------------------------------------------------------------
// K1: start/end projections. C[4096][1024] = A[4096][768] @ W[768][1024] + bias,
// then RoPE + 1/8 scale, stored bf16 to staging [bo][s][64].
//
// R5 retile: 64x128 blocks (was 128x128). Old grid 8x32 = 256 blocks = exactly
// 1 block/CU = 1 wave/SIMD -> every K-step's vmcnt(0)+barrier drain fully
// exposed (no co-resident block to overlap with). New grid 8x64 = 512 blocks
// = 2 blocks/CU. A-traffic unchanged (still 8 readers/row-panel); per-thread
// epilogue halves (32 sincos). 4 waves each 32x64 (2x4 MFMA tiles 16x16x32).
// ---------------------------------------------------------------------------
__global__ __launch_bounds__(256, 2)
void k1_proj_rope(const float* __restrict__ A,
                  const float* __restrict__ bs_p,
                  const float* __restrict__ be_p,
                  const unsigned short* __restrict__ Wt,
                  unsigned short* __restrict__ st_start,
                  unsigned short* __restrict__ st_end) {
  // sA padded to 72 elems/row (144B = 9 quads -> bank-balanced b128 reads).
  __shared__ __align__(16) unsigned short sA[64 * 72];
  // sB halves flat [128][32]: 64B row stride is quad-balanced; flat order
  // required by global_load_lds.
  __shared__ __align__(16) unsigned short sB0[128 * 32];
  __shared__ __align__(16) unsigned short sB1[128 * 32];

  const int t = threadIdx.x;
  const int lane = t & 63;
  const int w = t >> 6;
  const int m0 = blockIdx.y * 64;
  const int n0 = blockIdx.x * 128;
  const int wm = (w >> 1) * 32;
  const int wn = (w & 1) * 64;

  f32x4 acc[2][4];
#pragma unroll
  for (int i = 0; i < 2; i++)
#pragma unroll
    for (int j = 0; j < 4; j++) acc[i][j] = (f32x4){0.f, 0.f, 0.f, 0.f};

  for (int kt = 0; kt < 768; kt += 64) {
    __syncthreads();
    // B tiles: async global->LDS (already bf16). 8 chunks of 1KB per half.
#pragma unroll
    for (int h = 0; h < 2; h++) {
      unsigned short* sB = h ? sB1 : sB0;
#pragma unroll
      for (int j = 0; j < 2; j++) {
        const int c = w * 2 + j;               // chunk 0..7
        const int n = c * 16 + (lane >> 2);    // row within tile
        const int kk = (lane & 3) * 8;         // k offset within half
        gld_lds16(Wt + (size_t)(n0 + n) * 768 + kt + h * 32 + kk, sB + c * 512);
      }
    }
    // A tile: fp32 load + cvt + padded ds_write (64x64)
#pragma unroll
    for (int p = 0; p < 4; p++) {
      const int row = p * 16 + (t >> 4);
      const int kk = (t & 15) * 4;
      const float4 v = *(const float4*)(A + (size_t)(m0 + row) * 768 + kt + kk);
      ushort4 bv;
      bv.x = f2bf(v.x); bv.y = f2bf(v.y); bv.z = f2bf(v.z); bv.w = f2bf(v.w);
      *(ushort4*)(sA + row * 72 + kk) = bv;
    }
    __syncthreads();
#pragma unroll
    for (int s = 0; s < 2; s++) {
      const unsigned short* sB = s ? sB1 : sB0;
      bf16x8 af[2], bfr[4];
#pragma unroll
      for (int i = 0; i < 2; i++)
        af[i] = *(const bf16x8*)(sA + (wm + i * 16 + (lane & 15)) * 72 + s * 32 + (lane >> 4) * 8);
#pragma unroll
      for (int j = 0; j < 4; j++)
        bfr[j] = *(const bf16x8*)(sB + (wn + j * 16 + (lane & 15)) * 32 + (lane >> 4) * 8);
#pragma unroll
      for (int i = 0; i < 2; i++)
#pragma unroll
        for (int j = 0; j < 4; j++)
          acc[i][j] = __builtin_amdgcn_mfma_f32_16x16x32_bf16(af[i], bfr[j], acc[i][j], 0, 0, 0);
    }
  }

  // Epilogue: bias + RoPE + 0.125 scale, bf16 store to staging.
  // C/D layout: col = lane&15 (n), row = (lane>>4)*4 + reg (m)  [m89-verified]
#pragma unroll
  for (int j = 0; j < 4; j++) {
    const int n = n0 + wn + j * 16 + (lane & 15);  // 0..1023
    const int isEnd = n >= 512;
    const int nn = n & 511;
    const int o = nn >> 6;
    const int h = nn & 63;
    const float bias = isEnd ? be_p[nn] : bs_p[nn];
    // inv = 10000^(-(h%32)/32) = 2^(-(h%32)*log2(10000)/32)
    const float inv = exp2f(-(float)(h & 31) * 0.41524101186092f);
    const float sgn = (h & 1) ? 1.f : -1.f;  // rot[2k]=-x[2k+1], rot[2k+1]=x[2k]
    unsigned short* dst = isEnd ? st_end : st_start;
#pragma unroll
    for (int i = 0; i < 2; i++) {
#pragma unroll
      for (int r = 0; r < 4; r++) {
        const int m = m0 + wm + i * 16 + (lane >> 4) * 4 + r;
        const int sp = m & 2047;   // s position
        const int b = m >> 11;     // batch
        float val = acc[i][j][r] + bias;
        const float par = __shfl_xor(val, 1, 64);  // partner h^1 (same row)
        float sn, cs;
        __sincosf((float)sp * inv, &sn, &cs);
        const float outv = (val * cs + sgn * par * sn) * 0.125f;  // fold 1/sqrt(64)
        dst[(((size_t)(b * 8 + o) * 2048 + sp) << 6) + h] = f2bf(outv);
      }
    }
  }
}

// ---------------------------------------------------------------------------
// K2: logits[bo][m][n] = sum_d start[bo][m][d]*end[bo][n][d] (scale pre-folded)
// + mask + strict-lower-tril -1e12. 128x128 tiles, K=64 in one shot.
//
// R4: all output leaves as f32x4/lane, 512B-contiguous-per-32-lane (full 128B
// lines); compute tiles transpose through LDS ([64][132] f32 buffer reusing
// staging LDS).
// R5: drop `nontemporal` on stores. With full-line stores there is nothing
// left for the nt hint to win (staging refetch from L3 is cheap), and if nt
// demotes to non-combining writes at TCC it caps write BW. The harness fill
// (plain stores) hits 6.4 TB/s on this same buffer -> use the same path.
// ---------------------------------------------------------------------------
__global__ __launch_bounds__(256, 2)
void k2_logits(const unsigned short* __restrict__ st_start,
               const unsigned short* __restrict__ st_end,
               const float* __restrict__ mask,
               float* __restrict__ out) {
  // union: staging (sA 16KB | sB 16KB) then out-transpose buffer [64][132] f32
  __shared__ __align__(16) unsigned char smem[64 * 132 * 4];  // 33792 B
  unsigned short* sA = (unsigned short*)smem;
  unsigned short* sB = (unsigned short*)(smem + 16384);
  float* sOut = (float*)smem;

  const int t = threadIdx.x;
  const int lane = t & 63;
  const int w = t >> 6;
  const int bo = blockIdx.z;
  const int m0 = blockIdx.y * 128;
  const int n0 = blockIdx.x * 128;
  const int b = bo >> 3;
  const int wm = (w >> 1) * 64;
  const int wn = (w & 1) * 64;

  if (blockIdx.y > blockIdx.x) {
    // Entire tile strictly lower: out = (mv-1)*NEG - NEG, no matmul needed.
    // Value depends only on n -> one f32x4 per thread, 16 coalesced stores.
    const int c0 = (t & 31) * 4;                 // col offset within tile
    const f32x4 mv4 = *(const f32x4*)(mask + (size_t)b * 2048 + n0 + c0);
    f32x4 v;
#pragma unroll
    for (int c = 0; c < 4; c++) v[c] = (mv4[c] - 1.0f) * NEGV - NEGV;
#pragma unroll
    for (int it = 0; it < 16; it++) {
      const int row = it * 8 + (t >> 5);
      *(f32x4*)(out + ((size_t)bo * 2048 + m0 + row) * 2048 + n0 + c0) = v;
    }
    return;
  }

  const size_t abase = ((size_t)bo * 2048 + m0) * 64;
  const size_t bbase = ((size_t)bo * 2048 + n0) * 64;

  // LDS layout k-group-blocked [g][128][8]: lane-contiguous for global_load_lds
  // AND quad-balanced for ds_read_b128 fragment reads.
#pragma unroll
  for (int j = 0; j < 4; j++) {
    const int c = w * 4 + j;          // chunk 0..15 (1KB each)
    const int g = c >> 1;             // k-group 0..7
    const int mr = (c & 1) * 64 + lane;
    gld_lds16(st_start + abase + (size_t)mr * 64 + g * 8, sA + c * 512);
    gld_lds16(st_end + bbase + (size_t)mr * 64 + g * 8, sB + c * 512);
  }

  f32x4 acc[4][4];
#pragma unroll
  for (int i = 0; i < 4; i++)
#pragma unroll
    for (int j = 0; j < 4; j++) acc[i][j] = (f32x4){0.f, 0.f, 0.f, 0.f};

  __syncthreads();

#pragma unroll
  for (int s = 0; s < 2; s++) {
    const int g = s * 4 + (lane >> 4);
    bf16x8 af[4], bfr[4];
#pragma unroll
    for (int i = 0; i < 4; i++)
      af[i] = *(const bf16x8*)(sA + ((size_t)g * 128 + wm + i * 16 + (lane & 15)) * 8);
#pragma unroll
    for (int j = 0; j < 4; j++)
      bfr[j] = *(const bf16x8*)(sB + ((size_t)g * 128 + wn + j * 16 + (lane & 15)) * 8);
#pragma unroll
    for (int i = 0; i < 4; i++)
#pragma unroll
      for (int j = 0; j < 4; j++)
        acc[i][j] = __builtin_amdgcn_mfma_f32_16x16x32_bf16(af[i], bfr[j], acc[i][j], 0, 0, 0);
  }

  // Epilogue: two phases of 64 output rows each. Phase p handles MFMA row
  // tiles i in {2p, 2p+1}. Packed LDS row pr = (w>>1)*32 + ii*16 + q*4 + r
  // maps to global row m_l = (pr&31) + (pr>>5)*64 + p*32 (all waves busy in
  // both the scatter-write and the coalesced-store halves).
  // C/D: col = lane&15 = n, row = (lane>>4)*4+reg = m  [m89-verified]
#pragma unroll
  for (int p = 0; p < 2; p++) {
    __syncthreads();  // staging reads (p=0) / prior stores (p=1) done
#pragma unroll
    for (int j = 0; j < 4; j++) {
      const int n_l = wn + j * 16 + (lane & 15);
      const int n = n0 + n_l;
      const float mv = mask[(size_t)b * 2048 + n];
      const float basev = (mv - 1.0f) * NEGV;  // logits*pad - (1-pad)*NEG
#pragma unroll
      for (int ii = 0; ii < 2; ii++) {
        const int i = p * 2 + ii;
#pragma unroll
        for (int r = 0; r < 4; r++) {
          const int m_l = wm + i * 16 + (lane >> 4) * 4 + r;
          const int m = m0 + m_l;
          float v = acc[i][j][r] * mv + basev;
          if (m > n) v -= NEGV;  // tril(ones,-1): penalize m>n
          const int pr = (w >> 1) * 32 + ii * 16 + (lane >> 4) * 4 + r;
          sOut[pr * 132 + n_l] = v;
        }
      }
    }
    __syncthreads();
    // Coalesced drain: 64 rows x 512B, f32x4 per lane, full 128B lines.
    const int c0 = (t & 31) * 4;
#pragma unroll
    for (int it = 0; it < 8; it++) {
      const int prr = it * 8 + (t >> 5);
      const int m_l = (prr & 31) + ((prr >> 5) << 6) + p * 32;
      const f32x4 v4 = *(const f32x4*)(sOut + prr * 132 + c0);
      *(f32x4*)(out + ((size_t)bo * 2048 + m0 + m_l) * 2048 + n0 + c0) = v4;
    }
  }
}

// ---------------------------------------------------------------------------
extern "C" void kernel_launch(void* const* d_in, const int* in_sizes, int n_in,
                              void* d_out, int out_size, void* d_ws, size_t ws_size,
                              hipStream_t stream) {
  const float* inputs = (const float*)d_in[0];  // [2][2048][768]
  const float* mask   = (const float*)d_in[1];  // [2][2048]
  const float* Ws     = (const float*)d_in[2];  // [768][512]
  const float* bs     = (const float*)d_in[3];  // [512]
  const float* We     = (const float*)d_in[4];  // [768][512]
  const float* be     = (const float*)d_in[5];  // [512]
  float* out = (float*)d_out;                   // [2][8][2048][2048]

  // workspace: Wt bf16 [1024][768] | start [16][2048][64] | end [16][2048][64]
  unsigned short* Wt = (unsigned short*)d_ws;
  unsigned short* st_start = Wt + 1024 * 768;
  unsigned short* st_end = st_start + 16 * 2048 * 64;

  k0_transpose<<<dim3(16, 24, 2), 256, 0, stream>>>(Ws, We, Wt);
  k1_proj_rope<<<dim3(8, 64), 256, 0, stream>>>(inputs, bs, be, Wt, st_start, st_end);
  k2_logits<<<dim3(16, 16, 16), 256, 0, stream>>>(st_start, st_end, mask, out);
}